// Round 2
// baseline (1230.177 us; speedup 1.0000x reference)
//
#include <hip/hip_runtime.h>
#include <hip/hip_bf16.h>
#include <cstdint>

#define B_   8
#define T_   4096
#define D_   1024
#define M_   (B_*T_)      // 32768
#define K_   D_           // 1024
#define N_   D_           // 1024

#define TC   128          // scan chunk length
#define NC   (T_/TC)      // 32 chunks

#define BM   128
#define BN   128
#define BK   64

typedef __attribute__((ext_vector_type(8))) short  short8;
typedef __attribute__((ext_vector_type(4))) float  floatx4;

// ---- workspace layout (bytes) ----
#define XB_OFF    0ull                                   // x as bf16: 64 MiB
#define WR_OFF    (XB_OFF + (size_t)M_*K_*2)             // W_r bf16: 2 MiB
#define WI_OFF    (WR_OFF + (size_t)N_*K_*2)             // W_i bf16: 2 MiB
#define LS_OFF    (WI_OFF + (size_t)N_*K_*2)             // logsigmoid(lambd): 4 KiB
#define ASUM_OFF  (LS_OFF + (size_t)D_*4)                // chunk prod(a) -> carries: 1 MiB
#define ESUM_OFF  (ASUM_OFF + (size_t)B_*NC*D_*4)        // chunk h_end: 1 MiB
#define WS_NEED   (ESUM_OFF + (size_t)B_*NC*D_*4)

__device__ __forceinline__ uint32_t f2bf(float f) {
  uint32_t u = __float_as_uint(f);
  return (u + 0x7fffu + ((u >> 16) & 1u)) >> 16;   // RTNE bf16
}

__device__ __forceinline__ void gload_lds16(const void* g, void* l) {
  __builtin_amdgcn_global_load_lds(
      (const __attribute__((address_space(1))) void*)g,
      (__attribute__((address_space(3))) void*)l, 16, 0, 0);
}

// ---------------- Kernel A: fp32 -> bf16 conversion + logsigmoid(lambd) ----
__global__ __launch_bounds__(256) void convert_kernel(
    const float* __restrict__ x, const float* __restrict__ wr,
    const float* __restrict__ wi, const float* __restrict__ lambd,
    uint2* __restrict__ xb, uint2* __restrict__ wrb, uint2* __restrict__ wib,
    float* __restrict__ ls) {
  int gid = blockIdx.x * 256 + threadIdx.x;
  if (gid < D_) {
    float l = lambd[gid];
    // log_sigmoid(l) = min(l,0) - log1p(exp(-|l|)), stable
    ls[gid] = fminf(l, 0.f) - log1pf(__expf(-fabsf(l)));
  }
  const int XQ = M_*K_/4;   // float4 quads in x
  const int WQ = N_*K_/4;   // quads in each W
  int stride = gridDim.x * 256;
  for (int q = gid; q < XQ + 2*WQ; q += stride) {
    const float4* src; uint2* dst; int i;
    if (q < XQ)           { src = (const float4*)x;  dst = xb;  i = q; }
    else if (q < XQ + WQ) { src = (const float4*)wr; dst = wrb; i = q - XQ; }
    else                  { src = (const float4*)wi; dst = wib; i = q - XQ - WQ; }
    float4 v = src[i];
    uint2 o;
    o.x = (f2bf(v.y) << 16) | f2bf(v.x);
    o.y = (f2bf(v.w) << 16) | f2bf(v.z);
    dst[i] = o;
  }
}

// ---------------- Kernel B: dual GEMM (r & i gates) + fused gate epilogue ---
// grid: x = bm (fast-varying, 256), y = bn (8). Blocks sharing an A-tile are
// 256 apart in dispatch id -> same XCD (id%8) -> A re-reads hit that XCD's L2.
__global__ __launch_bounds__(256, 3) void dual_gemm_kernel(
    const short* __restrict__ xb, const short* __restrict__ wrb,
    const short* __restrict__ wib, const float* __restrict__ ls,
    const float* __restrict__ xf, uint32_t* __restrict__ ab) {
  __shared__ short lds[(BM + 2*BN) * BK];   // 48 KiB -> 3 blocks/CU
  short* As  = lds;                // [128 rows][64 k] bf16, XOR-swizzled chunks
  short* Brs = lds + BM*BK;
  short* Bis = lds + 2*BM*BK;

  const int tid  = threadIdx.x;
  const int lane = tid & 63;
  const int wv   = tid >> 6;       // wave 0..3
  const int wm   = wv >> 1;        // wave row (2x2 wave grid)
  const int wn   = wv & 1;
  const int c16  = lane & 15;
  const int q    = lane >> 4;      // quad 0..3

  const int bm = blockIdx.x * BM;
  const int bn = blockIdx.y * BN;

  floatx4 accR[4][4], accI[4][4];
  #pragma unroll
  for (int i = 0; i < 4; ++i)
    #pragma unroll
    for (int j = 0; j < 4; ++j) {
      accR[i][j] = (floatx4){0.f,0.f,0.f,0.f};
      accI[i][j] = (floatx4){0.f,0.f,0.f,0.f};
    }

  // staging geometry: one wave-load = 64 lanes x 16B = 8 rows x (8 chunks of 16B)
  // LDS chunk (r, c') holds global k-chunk c = c' ^ (r&7)  (XOR swizzle applied
  // on the global source address; LDS dest is fixed wave_base + lane*16)
  const int srow0  = wv*32 + (lane >> 3);
  const int schunk = lane & 7;

  for (int k0 = 0; k0 < K_; k0 += BK) {
    #pragma unroll
    for (int l = 0; l < 4; ++l) {
      int r  = srow0 + l*8;
      int cc = schunk ^ (r & 7);
      size_t goff = (size_t)k0 + cc*8;
      gload_lds16(xb  + (size_t)(bm + r)*K_ + goff, As  + wv*2048 + l*512);
      gload_lds16(wrb + (size_t)(bn + r)*K_ + goff, Brs + wv*2048 + l*512);
      gload_lds16(wib + (size_t)(bn + r)*K_ + goff, Bis + wv*2048 + l*512);
    }
    __syncthreads();   // compiler drains vmcnt before barrier

    #pragma unroll
    for (int kk = 0; kk < BK/32; ++kk) {
      short8 af[4], brf[4], bif[4];
      #pragma unroll
      for (int f = 0; f < 4; ++f) {
        int m_loc = wm*64 + f*16 + c16;
        int cph   = (kk*4 + q) ^ (m_loc & 7);
        af[f]  = *(const short8*)(As  + m_loc*64 + cph*8);
        int n_loc = wn*64 + f*16 + c16;
        int cphn  = (kk*4 + q) ^ (n_loc & 7);
        brf[f] = *(const short8*)(Brs + n_loc*64 + cphn*8);
        bif[f] = *(const short8*)(Bis + n_loc*64 + cphn*8);
      }
      #pragma unroll
      for (int fm = 0; fm < 4; ++fm)
        #pragma unroll
        for (int fn = 0; fn < 4; ++fn) {
          accR[fm][fn] = __builtin_amdgcn_mfma_f32_16x16x32_bf16(
              af[fm], brf[fn], accR[fm][fn], 0, 0, 0);
          accI[fm][fn] = __builtin_amdgcn_mfma_f32_16x16x32_bf16(
              af[fm], bif[fn], accI[fm][fn], 0, 0, 0);
        }
    }
    __syncthreads();   // protect LDS before next-tile staging
  }

  // epilogue: C/D layout (m89-verified): col = lane&15, row = quad*4 + reg
  #pragma unroll
  for (int fn = 0; fn < 4; ++fn) {
    int col = bn + wn*64 + fn*16 + c16;
    float lsv = ls[col];
    #pragma unroll
    for (int fm = 0; fm < 4; ++fm) {
      #pragma unroll
      for (int j = 0; j < 4; ++j) {
        int row = bm + wm*64 + fm*16 + q*4 + j;
        float pr = accR[fm][fn][j];
        float pi = accI[fm][fn][j];
        float rg = 1.f / (1.f + __expf(-pr));
        float ig = 1.f / (1.f + __expf(-pi));
        float la = 8.f * rg * lsv;               // log_a <= 0
        float xv = xf[(size_t)row*D_ + col];     // original fp32 x
        float a2 = __expf(2.f * la);
        float bb = sqrtf(fmaxf(1.f - a2, 0.f)) * ig * xv;
        ab[(size_t)row*N_ + col] = (f2bf(bb) << 16) | f2bf(la);
      }
    }
  }
}

// ---------------- Kernel C: per-chunk scan summaries (A = prod a, E = h_end) -
__global__ __launch_bounds__(256) void scan_summary(
    const uint32_t* __restrict__ ab, float* __restrict__ Asum,
    float* __restrict__ Esum) {
  int blk = blockIdx.x;              // B_ * NC * (D_/256) = 1024 blocks
  int dg = blk & 3;
  int c  = (blk >> 2) & (NC - 1);
  int b  = blk >> 7;
  int d  = (dg << 8) + threadIdx.x;
  const uint32_t* p = ab + ((size_t)(b*T_ + c*TC))*D_ + d;
  float A = 1.f, h = 0.f;
  #pragma unroll 4
  for (int t = 0; t < TC; ++t) {
    uint32_t v = p[(size_t)t * D_];
    float a  = __expf(__uint_as_float(v << 16));
    float bb = __uint_as_float(v & 0xffff0000u);
    A *= a;
    h = fmaf(a, h, bb);
  }
  int o = (b*NC + c)*D_ + d;
  Asum[o] = A;
  Esum[o] = h;
}

// ---------------- Kernel C2: turn (A,E) summaries into per-chunk carries ----
// Overwrites Asum[b,c,d] with carry = h state entering chunk c.
__global__ __launch_bounds__(256) void scan_carry(
    float* __restrict__ Asum, const float* __restrict__ Esum) {
  int b = blockIdx.x >> 2;                       // grid = B_*4 = 32 blocks
  int d = ((blockIdx.x & 3) << 8) + threadIdx.x;
  float carry = 0.f;
  for (int c = 0; c < NC; ++c) {
    int o = (b*NC + c)*D_ + d;
    float A = Asum[o], E = Esum[o];
    Asum[o] = carry;
    carry = fmaf(A, carry, E);
  }
}

// ---------------- Kernel D: final scan with precomputed carry, writes h -----
__global__ __launch_bounds__(256) void scan_final(
    uint32_t* __restrict__ out, const float* __restrict__ carry_buf) {
  int blk = blockIdx.x;
  int dg = blk & 3;
  int c  = (blk >> 2) & (NC - 1);
  int b  = blk >> 7;
  int d  = (dg << 8) + threadIdx.x;

  float h = carry_buf[(b*NC + c)*D_ + d];

  uint32_t* p = out + ((size_t)(b*T_ + c*TC))*D_ + d;
  #pragma unroll 4
  for (int t = 0; t < TC; ++t) {
    size_t o = (size_t)t * D_;
    uint32_t v = p[o];                       // read packed (log_a, b)
    float a = __expf(__uint_as_float(v << 16));
    h = fmaf(a, h, __uint_as_float(v & 0xffff0000u));
    p[o] = __float_as_uint(h);               // overwrite with h (fp32)
  }
}

extern "C" void kernel_launch(void* const* d_in, const int* in_sizes, int n_in,
                              void* d_out, int out_size, void* d_ws, size_t ws_size,
                              hipStream_t stream) {
  (void)in_sizes; (void)n_in; (void)out_size;
  if (ws_size < WS_NEED) return;   // need ~70 MiB scratch

  const float* x     = (const float*)d_in[0];
  const float* Wr    = (const float*)d_in[1];
  const float* Wi    = (const float*)d_in[2];
  const float* lambd = (const float*)d_in[3];

  char* ws = (char*)d_ws;
  short* xb   = (short*)(ws + XB_OFF);
  short* wrb  = (short*)(ws + WR_OFF);
  short* wib  = (short*)(ws + WI_OFF);
  float* ls   = (float*)(ws + LS_OFF);
  float* Asum = (float*)(ws + ASUM_OFF);
  float* Esum = (float*)(ws + ESUM_OFF);

  uint32_t* ab = (uint32_t*)d_out;   // packed (log_a, b) lives in d_out, then
                                     // scan_final overwrites it with h (fp32)

  convert_kernel<<<4096, 256, 0, stream>>>(x, Wr, Wi, lambd,
                                           (uint2*)xb, (uint2*)wrb, (uint2*)wib, ls);
  dual_gemm_kernel<<<dim3(M_/BM, N_/BN), 256, 0, stream>>>(xb, wrb, wib, ls, x, ab);
  scan_summary<<<B_ * NC * (D_/256), 256, 0, stream>>>(ab, Asum, Esum);
  scan_carry<<<B_ * 4, 256, 0, stream>>>(Asum, Esum);
  scan_final<<<B_ * NC * (D_/256), 256, 0, stream>>>(ab, Asum);
}

// Round 3
// 459.432 us; speedup vs baseline: 2.6776x; 2.6776x over previous
//
#include <hip/hip_runtime.h>
#include <hip/hip_bf16.h>
#include <cstdint>

#define B_   8
#define T_   4096
#define D_   1024
#define M_   (B_*T_)      // 32768
#define K_   D_           // 1024
#define N_   D_           // 1024

#define TC   128          // scan chunk length
#define NC   (T_/TC)      // 32 chunks

#define BM   128
#define BN   128
#define BK   64

typedef __attribute__((ext_vector_type(8))) short  short8;
typedef __attribute__((ext_vector_type(4))) float  floatx4;

// ---- workspace layout (bytes) ----
#define XB_OFF    0ull                                   // x as bf16: 64 MiB
#define WR_OFF    (XB_OFF + (size_t)M_*K_*2)             // W_r bf16: 2 MiB
#define WI_OFF    (WR_OFF + (size_t)N_*K_*2)             // W_i bf16: 2 MiB
#define LS_OFF    (WI_OFF + (size_t)N_*K_*2)             // logsigmoid(lambd): 4 KiB
#define ASUM_OFF  (LS_OFF + (size_t)D_*4)                // chunk prod(a) -> carries: 1 MiB
#define ESUM_OFF  (ASUM_OFF + (size_t)B_*NC*D_*4)        // chunk h_end: 1 MiB
#define WS_NEED   (ESUM_OFF + (size_t)B_*NC*D_*4)

__device__ __forceinline__ uint32_t f2bf(float f) {
  uint32_t u = __float_as_uint(f);
  return (u + 0x7fffu + ((u >> 16) & 1u)) >> 16;   // RTNE bf16
}

__device__ __forceinline__ void gload_lds16(const void* g, void* l) {
  __builtin_amdgcn_global_load_lds(
      (const __attribute__((address_space(1))) void*)g,
      (__attribute__((address_space(3))) void*)l, 16, 0, 0);
}

// ---------------- Kernel A: fp32 -> bf16 conversion + logsigmoid(lambd) ----
__global__ __launch_bounds__(256) void convert_kernel(
    const float* __restrict__ x, const float* __restrict__ wr,
    const float* __restrict__ wi, const float* __restrict__ lambd,
    uint2* __restrict__ xb, uint2* __restrict__ wrb, uint2* __restrict__ wib,
    float* __restrict__ ls) {
  int gid = blockIdx.x * 256 + threadIdx.x;
  if (gid < D_) {
    float l = lambd[gid];
    // log_sigmoid(l) = min(l,0) - log1p(exp(-|l|)), stable
    ls[gid] = fminf(l, 0.f) - log1pf(__expf(-fabsf(l)));
  }
  const int XQ = M_*K_/4;   // float4 quads in x
  const int WQ = N_*K_/4;   // quads in each W
  int stride = gridDim.x * 256;
  for (int q = gid; q < XQ + 2*WQ; q += stride) {
    const float4* src; uint2* dst; int i;
    if (q < XQ)           { src = (const float4*)x;  dst = xb;  i = q; }
    else if (q < XQ + WQ) { src = (const float4*)wr; dst = wrb; i = q - XQ; }
    else                  { src = (const float4*)wi; dst = wib; i = q - XQ - WQ; }
    float4 v = src[i];
    uint2 o;
    o.x = (f2bf(v.y) << 16) | f2bf(v.x);
    o.y = (f2bf(v.w) << 16) | f2bf(v.z);
    dst[i] = o;
  }
}

// ---------------- Kernel B: dual GEMM (r & i gates) + fused gate epilogue ---
// grid: x = bm (fast-varying, 256), y = bn (8). Blocks sharing an A-tile are
// 256 apart in dispatch id -> same XCD (id%8) -> A re-reads hit that XCD's L2.
// launch_bounds(256,2): wave needs ~236 regs (108 VGPR + 128 acc, unified
// file) -> 2 waves/EU is the hard ceiling; (256,3) spills catastrophically
// (R2: WRITE_SIZE 160MB->2GB, 947us).
__global__ __launch_bounds__(256, 2) void dual_gemm_kernel(
    const short* __restrict__ xb, const short* __restrict__ wrb,
    const short* __restrict__ wib, const float* __restrict__ ls,
    uint32_t* __restrict__ ab) {
  __shared__ short lds[(BM + 2*BN) * BK];   // 48 KiB
  short* As  = lds;                // [128 rows][64 k] bf16, XOR-swizzled chunks
  short* Brs = lds + BM*BK;
  short* Bis = lds + 2*BM*BK;

  const int tid  = threadIdx.x;
  const int lane = tid & 63;
  const int wv   = tid >> 6;       // wave 0..3
  const int wm   = wv >> 1;        // wave row (2x2 wave grid)
  const int wn   = wv & 1;
  const int c16  = lane & 15;
  const int q    = lane >> 4;      // quad 0..3

  const int bm = blockIdx.x * BM;
  const int bn = blockIdx.y * BN;

  floatx4 accR[4][4], accI[4][4];
  #pragma unroll
  for (int i = 0; i < 4; ++i)
    #pragma unroll
    for (int j = 0; j < 4; ++j) {
      accR[i][j] = (floatx4){0.f,0.f,0.f,0.f};
      accI[i][j] = (floatx4){0.f,0.f,0.f,0.f};
    }

  // staging geometry: one wave-load = 64 lanes x 16B = 8 rows x (8 chunks of 16B)
  // LDS chunk (r, c') holds global k-chunk c = c' ^ (r&7)  (XOR swizzle applied
  // on the global source address; LDS dest is fixed wave_base + lane*16)
  const int srow0  = wv*32 + (lane >> 3);
  const int schunk = lane & 7;

  for (int k0 = 0; k0 < K_; k0 += BK) {
    #pragma unroll
    for (int l = 0; l < 4; ++l) {
      int r  = srow0 + l*8;
      int cc = schunk ^ (r & 7);
      size_t goff = (size_t)k0 + cc*8;
      gload_lds16(xb  + (size_t)(bm + r)*K_ + goff, As  + wv*2048 + l*512);
      gload_lds16(wrb + (size_t)(bn + r)*K_ + goff, Brs + wv*2048 + l*512);
      gload_lds16(wib + (size_t)(bn + r)*K_ + goff, Bis + wv*2048 + l*512);
    }
    __syncthreads();   // compiler drains vmcnt before barrier

    #pragma unroll
    for (int kk = 0; kk < BK/32; ++kk) {
      short8 af[4], brf[4], bif[4];
      #pragma unroll
      for (int f = 0; f < 4; ++f) {
        int m_loc = wm*64 + f*16 + c16;
        int cph   = (kk*4 + q) ^ (m_loc & 7);
        af[f]  = *(const short8*)(As  + m_loc*64 + cph*8);
        int n_loc = wn*64 + f*16 + c16;
        int cphn  = (kk*4 + q) ^ (n_loc & 7);
        brf[f] = *(const short8*)(Brs + n_loc*64 + cphn*8);
        bif[f] = *(const short8*)(Bis + n_loc*64 + cphn*8);
      }
      #pragma unroll
      for (int fm = 0; fm < 4; ++fm)
        #pragma unroll
        for (int fn = 0; fn < 4; ++fn) {
          accR[fm][fn] = __builtin_amdgcn_mfma_f32_16x16x32_bf16(
              af[fm], brf[fn], accR[fm][fn], 0, 0, 0);
          accI[fm][fn] = __builtin_amdgcn_mfma_f32_16x16x32_bf16(
              af[fm], bif[fn], accI[fm][fn], 0, 0, 0);
        }
    }
    __syncthreads();   // protect LDS before next-tile staging
  }

  // epilogue: C/D layout (m89-verified): col = lane&15, row = quad*4 + reg
  // x re-read in bf16 (b is stored bf16 anyway -> no accuracy loss, half fetch)
  #pragma unroll
  for (int fn = 0; fn < 4; ++fn) {
    int col = bn + wn*64 + fn*16 + c16;
    float lsv = ls[col];
    #pragma unroll
    for (int fm = 0; fm < 4; ++fm) {
      #pragma unroll
      for (int j = 0; j < 4; ++j) {
        int row = bm + wm*64 + fm*16 + q*4 + j;
        float pr = accR[fm][fn][j];
        float pi = accI[fm][fn][j];
        float rg = 1.f / (1.f + __expf(-pr));
        float ig = 1.f / (1.f + __expf(-pi));
        float la = 8.f * rg * lsv;               // log_a <= 0
        uint32_t xu = (uint32_t)(uint16_t)xb[(size_t)row*K_ + col];
        float xv = __uint_as_float(xu << 16);
        float a2 = __expf(2.f * la);
        float bb = sqrtf(fmaxf(1.f - a2, 0.f)) * ig * xv;
        ab[(size_t)row*N_ + col] = (f2bf(bb) << 16) | f2bf(la);
      }
    }
  }
}

// ---------------- Kernel C: per-chunk scan summaries (A = prod a, E = h_end) -
__global__ __launch_bounds__(256) void scan_summary(
    const uint32_t* __restrict__ ab, float* __restrict__ Asum,
    float* __restrict__ Esum) {
  int blk = blockIdx.x;              // B_ * NC * (D_/256) = 1024 blocks
  int dg = blk & 3;
  int c  = (blk >> 2) & (NC - 1);
  int b  = blk >> 7;
  int d  = (dg << 8) + threadIdx.x;
  const uint32_t* p = ab + ((size_t)(b*T_ + c*TC))*D_ + d;
  float A = 1.f, h = 0.f;
  #pragma unroll 4
  for (int t = 0; t < TC; ++t) {
    uint32_t v = p[(size_t)t * D_];
    float a  = __expf(__uint_as_float(v << 16));
    float bb = __uint_as_float(v & 0xffff0000u);
    A *= a;
    h = fmaf(a, h, bb);
  }
  int o = (b*NC + c)*D_ + d;
  Asum[o] = A;
  Esum[o] = h;
}

// ---------------- Kernel C2: turn (A,E) summaries into per-chunk carries ----
// Overwrites Asum[b,c,d] with carry = h state entering chunk c.
__global__ __launch_bounds__(256) void scan_carry(
    float* __restrict__ Asum, const float* __restrict__ Esum) {
  int b = blockIdx.x >> 2;                       // grid = B_*4 = 32 blocks
  int d = ((blockIdx.x & 3) << 8) + threadIdx.x;
  float carry = 0.f;
  for (int c = 0; c < NC; ++c) {
    int o = (b*NC + c)*D_ + d;
    float A = Asum[o], E = Esum[o];
    Asum[o] = carry;
    carry = fmaf(A, carry, E);
  }
}

// ---------------- Kernel D: final scan with precomputed carry, writes h -----
__global__ __launch_bounds__(256) void scan_final(
    uint32_t* __restrict__ out, const float* __restrict__ carry_buf) {
  int blk = blockIdx.x;
  int dg = blk & 3;
  int c  = (blk >> 2) & (NC - 1);
  int b  = blk >> 7;
  int d  = (dg << 8) + threadIdx.x;

  float h = carry_buf[(b*NC + c)*D_ + d];

  uint32_t* p = out + ((size_t)(b*T_ + c*TC))*D_ + d;
  #pragma unroll 4
  for (int t = 0; t < TC; ++t) {
    size_t o = (size_t)t * D_;
    uint32_t v = p[o];                       // read packed (log_a, b)
    float a = __expf(__uint_as_float(v << 16));
    h = fmaf(a, h, __uint_as_float(v & 0xffff0000u));
    p[o] = __float_as_uint(h);               // overwrite with h (fp32)
  }
}

extern "C" void kernel_launch(void* const* d_in, const int* in_sizes, int n_in,
                              void* d_out, int out_size, void* d_ws, size_t ws_size,
                              hipStream_t stream) {
  (void)in_sizes; (void)n_in; (void)out_size;
  if (ws_size < WS_NEED) return;   // need ~70 MiB scratch

  const float* x     = (const float*)d_in[0];
  const float* Wr    = (const float*)d_in[1];
  const float* Wi    = (const float*)d_in[2];
  const float* lambd = (const float*)d_in[3];

  char* ws = (char*)d_ws;
  short* xb   = (short*)(ws + XB_OFF);
  short* wrb  = (short*)(ws + WR_OFF);
  short* wib  = (short*)(ws + WI_OFF);
  float* ls   = (float*)(ws + LS_OFF);
  float* Asum = (float*)(ws + ASUM_OFF);
  float* Esum = (float*)(ws + ESUM_OFF);

  uint32_t* ab = (uint32_t*)d_out;   // packed (log_a, b) lives in d_out, then
                                     // scan_final overwrites it with h (fp32)

  convert_kernel<<<4096, 256, 0, stream>>>(x, Wr, Wi, lambd,
                                           (uint2*)xb, (uint2*)wrb, (uint2*)wib, ls);
  dual_gemm_kernel<<<dim3(M_/BM, N_/BN), 256, 0, stream>>>(xb, wrb, wib, ls, ab);
  scan_summary<<<B_ * NC * (D_/256), 256, 0, stream>>>(ab, Asum, Esum);
  scan_carry<<<B_ * 4, 256, 0, stream>>>(Asum, Esum);
  scan_final<<<B_ * NC * (D_/256), 256, 0, stream>>>(ab, Asum);
}